// Round 6
// baseline (413.972 us; speedup 1.0000x reference)
//
#include <hip/hip_runtime.h>
#include <hip/hip_bf16.h>
#include <stdint.h>

// HMPNN layer: two NNConv(sum-agg)+sigmoid, concat, Linear(32,32), sigmoid.
// R4: fused edge dispatch, global atomics: edge 133us (atomic write-through).
// R5-R8: fine buckets. Learned: scattered 8B stores ~365GB/s (1 rec/line);
//     32-node buckets starve edge kernel (latency-bound).
// R9: coarse 512-node bins + per-(bin,ablock) runs. edge_mfma 205us at
//     OCCUPANCY 15% -- 392 blocks x 4 waves = 1568 waves starves the chip.
//     Scatter col stores still per-wave-scattered (~1.6 rec/line).
// R10: (1) bin_scatter: LDS-staged sort-by-bin (64KB stage), copy-out by
//         global index w/ binary search -> consecutive threads write
//         consecutive col slots (full lines). Zero global atomics.
//      (2) edge_mfma: 512 thr x SUBS=4 -> 784 blocks = 6272 waves,
//         3 blocks/CU (33KB LDS), same depth-2 MFMA core as passing R9.
//      Predict: scatter ~20us, edge 205->~60us (occ 15->60%), total ~150us.

#define NN 50000
#define EE 800000
#define SHIFT 9                 // 512 nodes per bin
#define CBIN 512
#define BPM 98                  // bins per metastep
#define ABLK 8192               // edges per scatter block
#define ABM 98                  // ceil(800000/8192)
#define CAPB_MAX 112            // per-(bin,ablock) cap: mean 84, sigma 9.1
#define SUBS 4                  // aggregation sub-blocks per bin
#define OVF_CAP (1 << 19)       // 512K spill entries (2 MB)

typedef __attribute__((ext_vector_type(8))) short short8;
typedef __attribute__((ext_vector_type(4))) float f32x4;

union U8 { short8 v; unsigned int u[4]; };

__device__ __forceinline__ unsigned short f2bf_rne(float f) {
    union { float fl; unsigned int i; } v; v.fl = f;
    unsigned int x = v.i;
    x += 0x7FFFu + ((x >> 16) & 1u);
    return (unsigned short)(x >> 16);
}

__device__ __forceinline__ unsigned int pack2bf(float a, float b) {
    __hip_bfloat162 h = __float22bfloat162_rn(float2{a, b}); // x=low, y=high
    union { __hip_bfloat162 h2; unsigned int u; } c; c.h2 = h;
    return c.u;
}

// B-fragment for MFMA step t: wf[t*512 + lane*8 + j].
// t<8 : W'[f = 8*q2 + t][i = qb*8 + j][n = lane&15]
// t==8: bias row: q2==0 -> b_msg[i][n], q2==1 -> 0
__global__ void prep_w(const float* __restrict__ w_msg_a, const float* __restrict__ b_msg_a,
                       unsigned short* __restrict__ wf_a,
                       const float* __restrict__ w_msg_b, const float* __restrict__ b_msg_b,
                       unsigned short* __restrict__ wf_b,
                       unsigned int* __restrict__ ovf_cnt) {
    if (blockIdx.x >= 2) {
        if (threadIdx.x == 0) *ovf_cnt = 0u;
        return;
    }
    const float* w_msg = blockIdx.x ? w_msg_b : w_msg_a;
    const float* b_msg = blockIdx.x ? b_msg_b : b_msg_a;
    unsigned short* wfrag = blockIdx.x ? wf_b : wf_a;
    for (int idx = threadIdx.x; idx < 9 * 64 * 8; idx += 256) {
        int j = idx & 7;
        int lane = (idx >> 3) & 63;
        int t = idx >> 9;
        int n = lane & 15;
        int qb = (lane >> 4) & 1;
        int q2 = (lane >> 5) & 1;
        int i = qb * 8 + j;
        int f = (t < 8) ? (8 * q2 + t) : (16 + q2);
        float v = (f < 16) ? w_msg[f * 256 + i * 16 + n]
                           : (f == 16 ? b_msg[i * 16 + n] : 0.f);
        wfrag[idx] = f2bf_rne(v);
    }
}

// 8192 edges per block. LDS histogram -> parallel prefix -> bin-sorted LDS
// staging -> copy-out by global index (binary search): consecutive threads
// write consecutive col slots => full-line stores. No global atomics.
__global__ __launch_bounds__(1024) void bin_scatter(
    const int* __restrict__ ei_a, const int* __restrict__ ei_b,
    unsigned int* __restrict__ cntA, uint2* __restrict__ col, int capb,
    unsigned int* __restrict__ ovf_cnt, unsigned int* __restrict__ ovf)
{
    int bid = blockIdx.x;
    int ms = bid >= ABM;
    int ablk = ms ? bid - ABM : bid;
    const int* __restrict__ ei = ms ? ei_b : ei_a;

    __shared__ uint2 stage[ABLK];           // 64 KB
    __shared__ unsigned int lcnt[BPM];
    __shared__ unsigned int loff[BPM + 1];

    int tid = threadIdx.x;
    if (tid < BPM) lcnt[tid] = 0u;
    __syncthreads();

    int e0 = ablk * ABLK;
    int srcv[8], dstv[8];
    unsigned int rr[8];
    #pragma unroll
    for (int k = 0; k < 8; ++k) {
        int e = e0 + k * 1024 + tid;
        bool v = e < EE;
        int dst = v ? ei[EE + e] : 0;
        int src = v ? ei[e] : 0;
        srcv[k] = src; dstv[k] = dst;
        rr[k] = v ? atomicAdd(&lcnt[dst >> SHIFT], 1u) : 0u;
    }
    __syncthreads();

    // parallel O(n^2) exclusive prefix (98 bins; broadcast-friendly reads)
    if (tid <= BPM) {
        unsigned int s = 0;
        for (int b = 0; b < tid; ++b) s += lcnt[b];
        loff[tid] = s;
    }
    if (tid < BPM)
        cntA[(size_t)(ms * BPM + tid) * ABM + ablk] = lcnt[tid];
    __syncthreads();

    // bin-sorted staging
    #pragma unroll
    for (int k = 0; k < 8; ++k) {
        int e = e0 + k * 1024 + tid;
        if (e >= EE) continue;
        int dst = dstv[k];
        int bin = dst >> SHIFT;
        stage[loff[bin] + rr[k]] =
            uint2{(unsigned int)srcv[k],
                  (unsigned int)(e | ((dst & (CBIN - 1)) << 20))};
    }
    __syncthreads();

    // coalesced copy-out: position i -> (bin b, rank p) via binary search
    int tot = (int)loff[BPM];
    for (int i = tid; i < tot; i += 1024) {
        int lo = 0, hi = BPM;
        while (hi - lo > 1) {
            int mid = (lo + hi) >> 1;
            if ((int)loff[mid] <= i) lo = mid; else hi = mid;
        }
        int p = i - (int)loff[lo];
        if (p < capb) {
            col[((size_t)(ms * BPM + lo) * ABM + ablk) * capb + p] = stage[i];
        } else {
            unsigned int q = atomicAdd(ovf_cnt, 1u);
            if (q < OVF_CAP)
                ovf[q] = (unsigned int)((stage[i].y & 0xFFFFFu) | (ms << 20));
        }
    }
}

// One block per (bin, ms, sub). 512 threads = 8 waves; 32 slices across the
// 4 sub-blocks; slice sl owns ablks sl, sl+32, ... Runs read contiguously;
// depth-2 pipeline; LDS atomics into 512x16 f32 tile; plain 32KB store of
// the partial tile (summed across subs in finalize). No global atomics.
__global__ __launch_bounds__(512) void edge_mfma(
    const float* __restrict__ ea_a, const float* __restrict__ x_a,
    const unsigned short* __restrict__ wf_a,
    const float* __restrict__ ea_b, const float* __restrict__ x_b,
    const unsigned short* __restrict__ wf_b,
    const unsigned int* __restrict__ cntA, const uint2* __restrict__ col,
    int capb, float* __restrict__ partial)
{
    int bid = blockIdx.x;
    int bin = bid >> 3;
    int ms  = (bid >> 2) & 1;
    int sub = bid & 3;
    const float* __restrict__ attr = ms ? ea_b : ea_a;
    const float* __restrict__ x    = ms ? x_b : x_a;
    const unsigned short* __restrict__ wfrag = ms ? wf_b : wf_a;

    __shared__ float tile[CBIN * 16];     // 32 KB
    __shared__ int s_len[ABM];

    int tid = threadIdx.x;
    for (int i = tid; i < CBIN * 16; i += 512) tile[i] = 0.f;
    size_t cbase = (size_t)(ms * BPM + bin) * ABM;
    if (tid < ABM) {
        int v = (int)cntA[cbase + tid];
        s_len[tid] = v < capb ? v : capb;
    }
    __syncthreads();

    int lane = tid & 63, wid = tid >> 6;
    int m = lane & 15, quad = lane >> 4;
    int q2 = quad >> 1, qb = quad & 1;

    short8 bfr[9];
    #pragma unroll
    for (int t = 0; t < 9; ++t)
        bfr[t] = ((const short8*)wfrag)[t * 64 + lane];

    const uint2* __restrict__ colb = col + cbase * capb;
    int sl = sub * 8 + wid;               // slice 0..31

    // descriptor: (g = ablk, ch = chunk-in-run, len = run length)
    int gC = sl, chC = 0, lenC = (gC < ABM) ? s_len[gC] : 0;
    while (gC < ABM && chC * 16 >= lenC) {
        gC += 32; chC = 0; lenC = (gC < ABM) ? s_len[gC] : 0;
    }

    bool vmC = false;
    uint2 peC = {0u, 0u};
    float4 xA = {0,0,0,0}, xB = {0,0,0,0}, aA = {0,0,0,0}, aB = {0,0,0,0};
    if (gC < ABM) {
        int slot = chC * 16 + m;
        vmC = slot < lenC;
        peC = vmC ? colb[(size_t)gC * capb + slot] : uint2{0u, 0u};
        const float4* xr = (const float4*)(x + (size_t)peC.x * 16);
        xA = xr[qb * 2]; xB = xr[qb * 2 + 1];
        const float4* ar = (const float4*)(attr + (size_t)(peC.y & 0xFFFFFu) * 16);
        aA = ar[q2 * 2]; aB = ar[q2 * 2 + 1];
    }

    while (gC < ABM) {
        int gN = gC, chN = chC + 1, lenN = lenC;
        while (gN < ABM && chN * 16 >= lenN) {
            gN += 32; chN = 0; lenN = (gN < ABM) ? s_len[gN] : 0;
        }
        bool vmN = false;
        uint2 peN = {0u, 0u};
        float4 xA2 = {0,0,0,0}, xB2 = {0,0,0,0}, aA2 = {0,0,0,0}, aB2 = {0,0,0,0};
        if (gN < ABM) {
            int slot = chN * 16 + m;
            vmN = slot < lenN;
            peN = vmN ? colb[(size_t)gN * capb + slot] : uint2{0u, 0u};
            const float4* xr = (const float4*)(x + (size_t)peN.x * 16);
            xA2 = xr[qb * 2]; xB2 = xr[qb * 2 + 1];
            const float4* ar = (const float4*)(attr + (size_t)(peN.y & 0xFFFFFu) * 16);
            aA2 = ar[q2 * 2]; aB2 = ar[q2 * 2 + 1];
        }

        float zf = vmC ? 1.f : 0.f;
        float xh[8] = {xA.x * zf, xA.y * zf, xA.z * zf, xA.w * zf,
                       xB.x * zf, xB.y * zf, xB.z * zf, xB.w * zf};
        float ah[8] = {aA.x, aA.y, aA.z, aA.w, aB.x, aB.y, aB.z, aB.w};

        f32x4 acc = {0.f, 0.f, 0.f, 0.f};
        #pragma unroll
        for (int t = 0; t < 8; ++t) {
            U8 a;
            #pragma unroll
            for (int jj = 0; jj < 4; ++jj)
                a.u[jj] = pack2bf(ah[t] * xh[2 * jj], ah[t] * xh[2 * jj + 1]);
            acc = __builtin_amdgcn_mfma_f32_16x16x32_bf16(a.v, bfr[t], acc, 0, 0, 0);
        }
        U8 a8;
        #pragma unroll
        for (int jj = 0; jj < 4; ++jj)
            a8.u[jj] = (q2 == 0) ? pack2bf(xh[2 * jj], xh[2 * jj + 1]) : 0u;
        acc = __builtin_amdgcn_mfma_f32_16x16x32_bf16(a8.v, bfr[8], acc, 0, 0, 0);

        int dl = (int)((peC.y >> 20) & (CBIN - 1));
        #pragma unroll
        for (int r = 0; r < 4; ++r) {
            int s2 = chC * 16 + quad * 4 + r;
            int dlr = __shfl(dl, quad * 4 + r);   // dlocal of edge slot quad*4+r
            if (s2 < lenC)
                atomicAdd(&tile[dlr * 16 + m], acc[r]);
        }

        gC = gN; chC = chN; lenC = lenN;
        vmC = vmN; peC = peN;
        xA = xA2; xB = xB2; aA = aA2; aB = aB2;
    }
    __syncthreads();

    float* __restrict__ pt =
        partial + ((size_t)(ms * BPM + bin) * SUBS + sub) * (CBIN * 16);
    for (int i = tid; i < CBIN * 16; i += 512) pt[i] = tile[i];
}

// Exact-f32 fallback for spilled edges: atomicAdd into the sub-0 partial
// tile (runs after edge_mfma's plain stores). Expected near-zero work.
__global__ __launch_bounds__(256) void ovf_cleanup(
    const int* __restrict__ ei_a, const float* __restrict__ ea_a,
    const float* __restrict__ x_a,
    const float* __restrict__ w_msg_a, const float* __restrict__ b_msg_a,
    const int* __restrict__ ei_b, const float* __restrict__ ea_b,
    const float* __restrict__ x_b,
    const float* __restrict__ w_msg_b, const float* __restrict__ b_msg_b,
    float* __restrict__ partial,
    const unsigned int* __restrict__ ovf_cnt, const unsigned int* __restrict__ ovf)
{
    unsigned int n = *ovf_cnt;
    if (n > OVF_CAP) n = OVF_CAP;
    int total = (int)n * 16;
    for (int idx = blockIdx.x * 256 + threadIdx.x; idx < total;
         idx += gridDim.x * 256) {
        int o = idx & 15;
        unsigned int rec = ovf[idx >> 4];
        int e = (int)(rec & 0xFFFFFu);
        int ms = (int)((rec >> 20) & 1u);
        const int* ei = ms ? ei_b : ei_a;
        const float* attr = ms ? ea_b : ea_a;
        const float* x = ms ? x_b : x_a;
        const float* w_msg = ms ? w_msg_b : w_msg_a;
        const float* b_msg = ms ? b_msg_b : b_msg_a;
        int src = ei[e], dst = ei[EE + e];
        const float* ar = attr + (size_t)e * 16;
        const float* xj = x + (size_t)src * 16;
        float acc = 0.f;
        #pragma unroll
        for (int i = 0; i < 16; ++i) {
            float we = b_msg[i * 16 + o];
            #pragma unroll
            for (int f = 0; f < 16; ++f)
                we += ar[f] * w_msg[f * 256 + i * 16 + o];
            acc += xj[i] * we;
        }
        size_t slot = ((size_t)(ms * BPM + (dst >> SHIFT)) * SUBS) * (CBIN * 16)
                      + (size_t)(dst & (CBIN - 1)) * 16 + o;
        atomicAdd(&partial[slot], acc);
    }
}

// out[n,d] = sigmoid( h @ w_lin + b_lin ),
// h = sigmoid( sum_subs partial + x@root + bias )
__global__ __launch_bounds__(256) void finalize(
    const float* __restrict__ xind, const float* __restrict__ partial,
    const float* __restrict__ root_a, const float* __restrict__ bias_a,
    const float* __restrict__ root_b, const float* __restrict__ bias_b,
    const float* __restrict__ w_lin, const float* __restrict__ b_lin,
    float* __restrict__ out)
{
    int tid = threadIdx.x;
    int n = blockIdx.x * 8 + (tid >> 5);
    if (n >= NN) return;
    int d = tid & 31;
    int lane = tid & 63;
    int gb32 = lane & ~31;

    float xv = xind[n * 16 + (d & 15)];

    int j = d & 15;
    int ms = (d < 16) ? 0 : 1;
    const float* root = ms ? root_b : root_a;
    const float* bias = ms ? bias_b : bias_a;

    int bin = n >> SHIFT, dl = n & (CBIN - 1);
    const float* pa = partial + ((size_t)(ms * BPM + bin) * SUBS) * (CBIN * 16)
                      + (size_t)dl * 16 + j;
    float acc = pa[0] + pa[CBIN * 16] + pa[2 * CBIN * 16] + pa[3 * CBIN * 16]
                + bias[j];
    #pragma unroll
    for (int i = 0; i < 16; ++i) {
        float xiv = __shfl(xv, gb32 + i);
        acc += xiv * root[i * 16 + j];
    }
    float h = 1.f / (1.f + __expf(-acc));

    float acc2 = b_lin[d];
    #pragma unroll
    for (int jj = 0; jj < 32; ++jj) {
        float hj = __shfl(h, gb32 + jj);
        acc2 += hj * w_lin[jj * 32 + d];
    }
    out[(size_t)n * 32 + d] = 1.f / (1.f + __expf(-acc2));
}

extern "C" void kernel_launch(void* const* d_in, const int* in_sizes, int n_in,
                              void* d_out, int out_size, void* d_ws, size_t ws_size,
                              hipStream_t stream) {
    (void)in_sizes; (void)n_in; (void)out_size;
    const float* x_indivi = (const float*)d_in[0];
    const float* x_src_a  = (const float*)d_in[1];
    const float* x_src_b  = (const float*)d_in[2];
    const int*   ei_a     = (const int*)d_in[3];
    const int*   ei_b     = (const int*)d_in[4];
    const float* ea_a     = (const float*)d_in[5];
    const float* ea_b     = (const float*)d_in[6];
    const float* w_msg_a  = (const float*)d_in[7];
    const float* b_msg_a  = (const float*)d_in[8];
    const float* root_a   = (const float*)d_in[9];
    const float* bias_a   = (const float*)d_in[10];
    const float* w_msg_b  = (const float*)d_in[11];
    const float* b_msg_b  = (const float*)d_in[12];
    const float* root_b   = (const float*)d_in[13];
    const float* bias_b   = (const float*)d_in[14];
    const float* w_lin    = (const float*)d_in[15];
    const float* b_lin    = (const float*)d_in[16];
    float* out = (float*)d_out;

    char* ws = (char*)d_ws;
    size_t off = 0;
    auto alloc = [&](size_t bytes) -> void* {
        void* p = ws + off;
        off += (bytes + 255) & ~(size_t)255;
        return p;
    };
    unsigned short* wf_a = (unsigned short*)alloc(9 * 64 * 8 * 2);       // 9216 B
    unsigned short* wf_b = (unsigned short*)alloc(9 * 64 * 8 * 2);
    unsigned int* cntA   = (unsigned int*)alloc((size_t)2 * BPM * ABM * 4); // 77 KB
    unsigned int* ovf_cnt = (unsigned int*)alloc(256);
    unsigned int* ovf    = (unsigned int*)alloc((size_t)OVF_CAP * 4);    // 2 MB
    float* partial = (float*)alloc((size_t)2 * BPM * SUBS * CBIN * 16 * 4); // 25.7 MB
    // col sized from remaining workspace; capb <= 112 (mean 84, sigma 9.1).
    // Any shrink is safe: overflow edges go through ovf_cleanup (exact f32).
    size_t avail = ws_size > off ? ws_size - off : 0;
    int capb = (int)(avail / ((size_t)2 * BPM * ABM * 8));
    if (capb > CAPB_MAX) capb = CAPB_MAX;
    uint2* col = (uint2*)(ws + off);

    prep_w<<<3, 256, 0, stream>>>(w_msg_a, b_msg_a, wf_a,
                                  w_msg_b, b_msg_b, wf_b, ovf_cnt);

    bin_scatter<<<2 * ABM, 1024, 0, stream>>>(ei_a, ei_b, cntA, col, capb,
                                              ovf_cnt, ovf);

    edge_mfma<<<BPM * 2 * SUBS, 512, 0, stream>>>(
        ea_a, x_src_a, wf_a, ea_b, x_src_b, wf_b, cntA, col, capb, partial);

    ovf_cleanup<<<64, 256, 0, stream>>>(
        ei_a, ea_a, x_src_a, w_msg_a, b_msg_a,
        ei_b, ea_b, x_src_b, w_msg_b, b_msg_b, partial, ovf_cnt, ovf);

    finalize<<<(NN + 7) / 8, 256, 0, stream>>>(
        x_indivi, partial, root_a, bias_a, root_b, bias_b, w_lin, b_lin, out);
}